// Round 1
// baseline (3125.471 us; speedup 1.0000x reference)
//
#include <hip/hip_runtime.h>
#include <hip/hip_bf16.h>
#include <stdint.h>

#define B_ 64
#define T_ 512
#define I_ 1024
#define H_ 1024
#define BH (B_*H_)

typedef __attribute__((ext_vector_type(8))) short short8;
typedef __attribute__((ext_vector_type(4))) float f32x4;

static __device__ __forceinline__ unsigned short f2bf(float f) {
  union { float f; unsigned u; } v; v.f = f;
  unsigned r = v.u + 0x7fffu + ((v.u >> 16) & 1u);
  return (unsigned short)(r >> 16);
}

static __device__ __forceinline__ void glds16(const void* g, void* l) {
  __builtin_amdgcn_global_load_lds(
      (const __attribute__((address_space(1))) unsigned int*)g,
      (__attribute__((address_space(3))) unsigned int*)l, 16, 0, 0);
}

// ---------------- weight conversion f32 -> bf16 ----------------
__global__ void convert_weights(const f32x4* __restrict__ wih, const f32x4* __restrict__ whh,
                                uint2* __restrict__ wih_b, uint2* __restrict__ whh_b)
{
  int idx = blockIdx.x * blockDim.x + threadIdx.x;   // 262144 threads, 4 elems each
  f32x4 a = wih[idx];
  uint2 o;
  o.x = f2bf(a[0]) | ((unsigned)f2bf(a[1]) << 16);
  o.y = f2bf(a[2]) | ((unsigned)f2bf(a[3]) << 16);
  wih_b[idx] = o;
  f32x4 b = whh[idx];
  uint2 p;
  p.x = f2bf(b[0]) | ((unsigned)f2bf(b[1]) << 16);
  p.y = f2bf(b[2]) | ((unsigned)f2bf(b[3]) << 16);
  whh_b[idx] = p;
}

// ---------------- x_proj GEMM: out[t*BH + b*H + n] = input[b,t,:]*W_ih[n,:] + bias ----------------
__launch_bounds__(256)
__global__ void gemm_xproj(const float* __restrict__ in,
                           const unsigned short* __restrict__ wb,
                           const float* __restrict__ bih,
                           const float* __restrict__ bhh,
                           float* __restrict__ out)
{
  __shared__ __align__(16) unsigned char As[16384];   // 128 rows x 64 bf16 (swizzled)
  __shared__ __align__(16) unsigned char Bs[16384];   // 128 rows x 64 bf16 (swizzled)
  const int tid = threadIdx.x;
  const int lane = tid & 63;
  const int w = tid >> 6;
  const int wm = w >> 1, wn = w & 1;
  const int bn = blockIdx.x, bm = blockIdx.y;

  // A staging role: thread covers row ar, k-half ah (32 f32)
  const int ar = tid >> 1;
  const int ah = tid & 1;
  const int R0 = bm*128 + ar;
  const float* asrc = in + (size_t)(R0 & 63) * (T_*I_) + (size_t)(R0 >> 6) * I_ + ah*32;
  unsigned char* adst_base = As + ar*128;
  const int aswz_w = (ar & 7) << 4;

  f32x4 acc[4][4];
  #pragma unroll
  for (int i = 0; i < 4; ++i)
    #pragma unroll
    for (int j = 0; j < 4; ++j)
      acc[i][j] = (f32x4){0.f,0.f,0.f,0.f};

  f32x4 av[8];
  #pragma unroll
  for (int j = 0; j < 8; ++j) av[j] = *(const f32x4*)(asrc + 0*64 + j*4);

  for (int kt = 0; kt < 16; ++kt) {
    __syncthreads();   // previous compute done before LDS overwrite
    // B stage via global_load_lds (linear LDS dest, source pre-swizzled)
    #pragma unroll
    for (int q = 0; q < 4; ++q) {
      int inst = w*4 + q;
      int rb = inst*8 + (lane >> 3);
      int srcoff = ((bn*128 + rb) * I_ + kt*64) * 2 + (((lane & 7) * 16) ^ ((rb & 7) << 4));
      glds16((const unsigned char*)wb + srcoff, Bs + inst*1024);
    }
    // A convert + swizzled ds_write
    #pragma unroll
    for (int j2 = 0; j2 < 4; ++j2) {
      uint4 val;
      f32x4 v0 = av[j2*2], v1 = av[j2*2+1];
      val.x = f2bf(v0[0]) | ((unsigned)f2bf(v0[1]) << 16);
      val.y = f2bf(v0[2]) | ((unsigned)f2bf(v0[3]) << 16);
      val.z = f2bf(v1[0]) | ((unsigned)f2bf(v1[1]) << 16);
      val.w = f2bf(v1[2]) | ((unsigned)f2bf(v1[3]) << 16);
      int koffb = ah*64 + j2*16;
      *(uint4*)(adst_base + (koffb ^ aswz_w)) = val;
    }
    __syncthreads();   // glds + ds_writes complete
    // prefetch next A tile (overlaps MFMA)
    if (kt < 15) {
      #pragma unroll
      for (int j = 0; j < 8; ++j) av[j] = *(const f32x4*)(asrc + (kt+1)*64 + j*4);
    }
    // compute
    #pragma unroll
    for (int kb = 0; kb < 2; ++kb) {
      const int kby = kb*64 + ((lane >> 4) << 4);
      short8 af[4], bfr[4];
      #pragma unroll
      for (int i = 0; i < 4; ++i) {
        int ra = wm*64 + i*16 + (lane & 15);
        af[i] = *(const short8*)(As + ra*128 + (kby ^ ((ra & 7) << 4)));
      }
      #pragma unroll
      for (int j = 0; j < 4; ++j) {
        int rb2 = wn*64 + j*16 + (lane & 15);
        bfr[j] = *(const short8*)(Bs + rb2*128 + (kby ^ ((rb2 & 7) << 4)));
      }
      #pragma unroll
      for (int i = 0; i < 4; ++i)
        #pragma unroll
        for (int j = 0; j < 4; ++j)
          acc[i][j] = __builtin_amdgcn_mfma_f32_16x16x32_bf16(af[i], bfr[j], acc[i][j], 0, 0, 0);
    }
  }
  // epilogue: add bias, scatter to (T,B,H)
  #pragma unroll
  for (int j = 0; j < 4; ++j) {
    int col = bn*128 + wn*64 + j*16 + (lane & 15);
    float bias = bih[col] + bhh[col];
    #pragma unroll
    for (int i = 0; i < 4; ++i) {
      int Rb = bm*128 + wm*64 + i*16 + ((lane >> 4) << 2);
      #pragma unroll
      for (int q = 0; q < 4; ++q) {
        int R = Rb + q;
        out[(size_t)(R >> 6) * BH + (size_t)(R & 63) * H_ + col] = acc[i][j][q] + bias;
      }
    }
  }
}

// ---------------- recurrence: 64 persistent WGs, per-step group barrier ----------------
// WG g: gb = g>>4 (batch group of 16 rows), gn = g&15 (64-column slice).
// LDS: W_hh slice [64][1024] bf16 (128KB, XOR-swizzled) + h tile [16][1024] bf16 (32KB).
__launch_bounds__(256, 1)
__global__ void rnn_recur(const unsigned short* __restrict__ whh_b,
                          float* __restrict__ out,
                          unsigned short* __restrict__ hbuf0,
                          unsigned short* __restrict__ hbuf1,
                          unsigned int* __restrict__ cnt)
{
  extern __shared__ __align__(16) unsigned char lds[];
  unsigned char* Ws = lds;             // 131072 B
  unsigned char* hs = lds + 131072;    // 32768 B
  const int tid = threadIdx.x;
  const int lane = tid & 63;
  const int w = tid >> 6;
  const int g = blockIdx.x;
  const int gb = g >> 4;
  const int gn = g & 15;

  // ---- one-time W_hh slice load (linear LDS dest, pre-swizzled global source) ----
  for (int q = 0; q < 32; ++q) {
    int inst = w*32 + q;                 // 0..127, 1KB each; 2 insts per 2048B row
    int nl = inst >> 1;                  // local col-row 0..63 (wave-uniform)
    int koff = (inst & 1)*1024 + lane*16;
    size_t srcoff = (size_t)(gn*64 + nl)*2048 + (size_t)(koff ^ ((nl & 7) << 4));
    glds16((const unsigned char*)whh_b + srcoff, Ws + inst*1024);
  }
  asm volatile("s_waitcnt vmcnt(0)" ::: "memory");
  __syncthreads();

  // per-thread output mapping: D[n][b], col=lane&15 -> b, row=(lane>>4)*4+q -> n'
  const int bb = lane & 15;
  const int nq = (lane >> 4) << 2;
  const int colb = gn*64 + w*16 + nq;          // global H col base (4 consecutive)
  const int brow = gb*16 + bb;                 // global batch row

  // staging roles
  const int sr = tid >> 4;                     // hs row 0..15
  const int sc = tid & 15;                     // 128B chunk
  unsigned char* hsrow = hs + sr*2048;
  const int swz_s = (sr & 7) << 4;

  // fragment addressing
  const int arow = w*16 + (lane & 15);         // Ws row (A-operand: W rows = n)
  const unsigned char* wsrow = Ws + (size_t)arow*2048;
  const int aswz = (arow & 7) << 4;
  const unsigned char* hfrow = hs + (size_t)bb*2048;   // hs row (B-operand: h rows = b)
  const int bswz = (bb & 7) << 4;
  const int klane = (lane >> 4) << 4;          // k-byte sub-offset

  unsigned int* mycnt = cnt + gb*64;           // 256B-spaced counters

  for (int t = 0; t < T_; ++t) {
    if (t > 0) {
      if (tid == 0) {
        unsigned target = (unsigned)(16*t);
        while (__hip_atomic_load(mycnt, __ATOMIC_RELAXED, __HIP_MEMORY_SCOPE_AGENT) < target)
          __builtin_amdgcn_s_sleep(1);
      }
      __syncthreads();
      const unsigned short* hb = (t & 1) ? hbuf1 : hbuf0;
      const unsigned char* srcrow = (const unsigned char*)hb + (size_t)(gb*16 + sr)*2048 + sc*128;
      unsigned long long hv[16];
      #pragma unroll
      for (int j = 0; j < 16; ++j)
        hv[j] = __hip_atomic_load((const unsigned long long*)(srcrow + j*8),
                                  __ATOMIC_RELAXED, __HIP_MEMORY_SCOPE_AGENT);
      #pragma unroll
      for (int j2 = 0; j2 < 8; ++j2) {
        uint4 val;
        val.x = (unsigned)hv[2*j2];
        val.y = (unsigned)(hv[2*j2] >> 32);
        val.z = (unsigned)hv[2*j2+1];
        val.w = (unsigned)(hv[2*j2+1] >> 32);
        *(uint4*)(hsrow + ((sc*128 + j2*16) ^ swz_s)) = val;
      }
    } else {
      uint4 z = {0u,0u,0u,0u};
      #pragma unroll
      for (int j2 = 0; j2 < 8; ++j2)
        *(uint4*)(hsrow + ((sc*128 + j2*16) ^ swz_s)) = z;
    }
    // x_proj slice for this thread's 4 outputs (read before overwrite; same thread owns it)
    f32x4 xp = *(const f32x4*)(out + (size_t)t*BH + (size_t)brow*H_ + colb);
    __syncthreads();

    // K=1024 MFMA chain, 2 independent accumulators
    f32x4 acc0 = (f32x4){0.f,0.f,0.f,0.f}, acc1 = (f32x4){0.f,0.f,0.f,0.f};
    #pragma unroll
    for (int kb = 0; kb < 32; kb += 2) {
      short8 a0 = *(const short8*)(wsrow + ((kb*64 + klane) ^ aswz));
      short8 b0 = *(const short8*)(hfrow + ((kb*64 + klane) ^ bswz));
      short8 a1 = *(const short8*)(wsrow + (((kb+1)*64 + klane) ^ aswz));
      short8 b1 = *(const short8*)(hfrow + (((kb+1)*64 + klane) ^ bswz));
      acc0 = __builtin_amdgcn_mfma_f32_16x16x32_bf16(a0, b0, acc0, 0, 0, 0);
      acc1 = __builtin_amdgcn_mfma_f32_16x16x32_bf16(a1, b1, acc1, 0, 0, 0);
    }
    f32x4 hval;
    #pragma unroll
    for (int q = 0; q < 4; ++q)
      hval[q] = tanhf(acc0[q] + acc1[q] + xp[q]);

    // output h[t] (overwrites x_proj[t] slice we own)
    *(f32x4*)(out + (size_t)t*BH + (size_t)brow*H_ + colb) = hval;
    if (t == T_-1)
      *(f32x4*)(out + (size_t)T_*BH + (size_t)brow*H_ + colb) = hval;   // h_last

    // bf16 h to exchange buffer (agent-coherent)
    unsigned long long pk =
        (unsigned long long)(f2bf(hval[0]) | ((unsigned)f2bf(hval[1]) << 16)) |
        ((unsigned long long)(f2bf(hval[2]) | ((unsigned)f2bf(hval[3]) << 16)) << 32);
    unsigned short* hw = (t & 1) ? hbuf0 : hbuf1;
    __hip_atomic_store((unsigned long long*)((unsigned char*)hw + (size_t)brow*2048 + (size_t)colb*2),
                       pk, __ATOMIC_RELAXED, __HIP_MEMORY_SCOPE_AGENT);
    asm volatile("s_waitcnt vmcnt(0)" ::: "memory");
    __syncthreads();
    if (tid == 0)
      __hip_atomic_fetch_add(mycnt, 1u, __ATOMIC_RELAXED, __HIP_MEMORY_SCOPE_AGENT);
  }
}

extern "C" void kernel_launch(void* const* d_in, const int* in_sizes, int n_in,
                              void* d_out, int out_size, void* d_ws, size_t ws_size,
                              hipStream_t stream)
{
  const float* in  = (const float*)d_in[0];
  const float* wih = (const float*)d_in[1];
  const float* whh = (const float*)d_in[2];
  const float* bih = (const float*)d_in[3];
  const float* bhh = (const float*)d_in[4];
  float* out = (float*)d_out;
  unsigned char* ws = (unsigned char*)d_ws;

  unsigned int*  cnt   = (unsigned int*)ws;                              // 4KB counters
  unsigned short* hbuf0 = (unsigned short*)(ws + 4096);                  // 128KB
  unsigned short* hbuf1 = (unsigned short*)(ws + 4096 + 131072);         // 128KB
  unsigned short* wih_b = (unsigned short*)(ws + 4096 + 262144);         // 2MB
  unsigned short* whh_b = (unsigned short*)(ws + 4096 + 262144 + 2097152); // 2MB

  hipMemsetAsync(cnt, 0, 4096, stream);
  convert_weights<<<1024, 256, 0, stream>>>((const f32x4*)wih, (const f32x4*)whh,
                                            (uint2*)wih_b, (uint2*)whh_b);
  gemm_xproj<<<dim3(8, 256), 256, 0, stream>>>(in, wih_b, bih, bhh, out);
  rnn_recur<<<64, 256, 163840, stream>>>(whh_b, out, hbuf0, hbuf1, cnt);
}